// Round 1
// baseline (66.864 us; speedup 1.0000x reference)
//
#include <hip/hip_runtime.h>
#include <math.h>

#define N_PTS 8192
#define BATCH 2
#define QBLK 256                    // queries per block (1 per thread)
#define CHUNK 1024                  // DB points per block chunk (12 KB LDS)
#define NCHUNK (N_PTS / CHUNK)      // 8
#define NQBLK (N_PTS / QBLK)        // 32
#define TOTQ (BATCH * 2 * N_PTS)    // 32768 query slots (both directions)

// ws layout: [0 .. TOTQ) uint32 min-bits, then 1 float accumulator
__global__ __launch_bounds__(256) void chamfer_init(unsigned int* __restrict__ minbits,
                                                    float* __restrict__ accum) {
    int i = blockIdx.x * blockDim.x + threadIdx.x;
    if (i < TOTQ) minbits[i] = 0x7F7FFFFFu;  // FLT_MAX bits
    if (i == 0) *accum = 0.0f;
}

__global__ __launch_bounds__(QBLK) void chamfer_nn(const float* __restrict__ pc1,
                                                   const float* __restrict__ pc2,
                                                   const float* __restrict__ flow,
                                                   unsigned int* __restrict__ minbits) {
    __shared__ float db[CHUNK * 3];

    const int qblock = blockIdx.x % NQBLK;
    const int chunk  = blockIdx.x / NQBLK;
    const int b      = blockIdx.y;
    const int dir    = blockIdx.z;
    const int tid    = threadIdx.x;

    const float* base1 = pc1  + (size_t)b * N_PTS * 3;
    const float* base2 = pc2  + (size_t)b * N_PTS * 3;
    const float* basef = flow + (size_t)b * N_PTS * 3;

    // Stage DB chunk in LDS. dir 0: DB = pc2. dir 1: DB = pc1 + flow (warped).
    const int dbBase = chunk * CHUNK * 3;
    if (dir == 0) {
        for (int i = tid; i < CHUNK * 3; i += QBLK)
            db[i] = base2[dbBase + i];
    } else {
        for (int i = tid; i < CHUNK * 3; i += QBLK)
            db[i] = base1[dbBase + i] + basef[dbBase + i];
    }
    __syncthreads();

    // Per-thread query point. dir 0: q = pc1 + flow. dir 1: q = pc2.
    const int qi = qblock * QBLK + tid;
    float qx, qy, qz;
    if (dir == 0) {
        qx = base1[qi * 3 + 0] + basef[qi * 3 + 0];
        qy = base1[qi * 3 + 1] + basef[qi * 3 + 1];
        qz = base1[qi * 3 + 2] + basef[qi * 3 + 2];
    } else {
        qx = base2[qi * 3 + 0];
        qy = base2[qi * 3 + 1];
        qz = base2[qi * 3 + 2];
    }

    // 4 independent min accumulators to break the v_min dependency chain.
    float m0 = 3.402823466e38f, m1 = m0, m2 = m0, m3 = m0;
    #pragma unroll 8
    for (int j = 0; j < CHUNK; j += 4) {
        // All 64 lanes read the same LDS address -> broadcast, conflict-free.
        float dx0 = qx - db[(j + 0) * 3 + 0];
        float dy0 = qy - db[(j + 0) * 3 + 1];
        float dz0 = qz - db[(j + 0) * 3 + 2];
        float d0  = dx0 * dx0 + dy0 * dy0 + dz0 * dz0;
        float dx1 = qx - db[(j + 1) * 3 + 0];
        float dy1 = qy - db[(j + 1) * 3 + 1];
        float dz1 = qz - db[(j + 1) * 3 + 2];
        float d1  = dx1 * dx1 + dy1 * dy1 + dz1 * dz1;
        float dx2 = qx - db[(j + 2) * 3 + 0];
        float dy2 = qy - db[(j + 2) * 3 + 1];
        float dz2 = qz - db[(j + 2) * 3 + 2];
        float d2  = dx2 * dx2 + dy2 * dy2 + dz2 * dz2;
        float dx3 = qx - db[(j + 3) * 3 + 0];
        float dy3 = qy - db[(j + 3) * 3 + 1];
        float dz3 = qz - db[(j + 3) * 3 + 2];
        float d3  = dx3 * dx3 + dy3 * dy3 + dz3 * dz3;
        m0 = fminf(m0, d0);
        m1 = fminf(m1, d1);
        m2 = fminf(m2, d2);
        m3 = fminf(m3, d3);
    }
    float m = fminf(fminf(m0, m1), fminf(m2, m3));

    // Combine across DB chunks. d2 >= 0 so uint-bit ordering == float ordering.
    atomicMin(&minbits[((size_t)(dir * BATCH + b) * N_PTS) + qi], __float_as_uint(m));
}

__global__ __launch_bounds__(256) void chamfer_reduce(const unsigned int* __restrict__ minbits,
                                                      float* __restrict__ accum) {
    int i = blockIdx.x * blockDim.x + threadIdx.x;
    float v = (i < TOTQ) ? sqrtf(__uint_as_float(minbits[i])) : 0.0f;
    // wave-64 shuffle reduce
    for (int off = 32; off > 0; off >>= 1)
        v += __shfl_down(v, off, 64);
    __shared__ float wsum[4];
    const int wave = threadIdx.x >> 6;
    if ((threadIdx.x & 63) == 0) wsum[wave] = v;
    __syncthreads();
    if (threadIdx.x == 0) {
        atomicAdd(accum, wsum[0] + wsum[1] + wsum[2] + wsum[3]);
    }
}

__global__ void chamfer_finalize(const float* __restrict__ accum, float* __restrict__ out) {
    out[0] = accum[0] * (1.0f / (float)(BATCH * N_PTS));
}

extern "C" void kernel_launch(void* const* d_in, const int* in_sizes, int n_in,
                              void* d_out, int out_size, void* d_ws, size_t ws_size,
                              hipStream_t stream) {
    const float* pc1  = (const float*)d_in[0];
    const float* pc2  = (const float*)d_in[1];
    const float* flow = (const float*)d_in[2];
    float* out = (float*)d_out;

    unsigned int* minbits = (unsigned int*)d_ws;
    float* accum = (float*)(minbits + TOTQ);

    chamfer_init<<<(TOTQ + 255) / 256, 256, 0, stream>>>(minbits, accum);

    dim3 grid(NQBLK * NCHUNK, BATCH, 2);
    chamfer_nn<<<grid, QBLK, 0, stream>>>(pc1, pc2, flow, minbits);

    chamfer_reduce<<<(TOTQ + 255) / 256, 256, 0, stream>>>(minbits, accum);
    chamfer_finalize<<<1, 1, 0, stream>>>(accum, out);
}

// Round 2
// 52.450 us; speedup vs baseline: 1.2748x; 1.2748x over previous
//
#include <hip/hip_runtime.h>
#include <math.h>

#define N_PTS   8192
#define BATCH   2
#define NTHR    256
#define QPT     2                      // queries per thread
#define QPB     (NTHR * QPT)           // 512 queries per block
#define NQB     (N_PTS / QPB)          // 16
#define NCHUNK  16
#define CHUNKC  (N_PTS / NCHUNK)       // 512 candidates per chunk
#define TOTQ    (BATCH * 2 * N_PTS)    // 32768 query slots

// ws layout:
//   cand : float4[2][BATCH][N_PTS]   set0 = pc2, set1 = pc1+flow   (1 MB)
//          cand[i] = (-2px, -2py, -2pz, |p|^2)
//   res  : float[NCHUNK][TOTQ]       per-chunk min d^2              (2 MB)
//   accum: float

__global__ __launch_bounds__(256) void chamfer_prep(const float* __restrict__ pc1,
                                                    const float* __restrict__ pc2,
                                                    const float* __restrict__ flow,
                                                    float4* __restrict__ cand,
                                                    float* __restrict__ accum) {
    int i = blockIdx.x * 256 + threadIdx.x;     // 0 .. BATCH*N_PTS-1  (= b*N + j)
    if (i < BATCH * N_PTS) {
        float px = pc2[i * 3 + 0], py = pc2[i * 3 + 1], pz = pc2[i * 3 + 2];
        cand[i] = make_float4(-2.f * px, -2.f * py, -2.f * pz,
                              px * px + py * py + pz * pz);
        float wx = pc1[i * 3 + 0] + flow[i * 3 + 0];
        float wy = pc1[i * 3 + 1] + flow[i * 3 + 1];
        float wz = pc1[i * 3 + 2] + flow[i * 3 + 2];
        cand[BATCH * N_PTS + i] = make_float4(-2.f * wx, -2.f * wy, -2.f * wz,
                                              wx * wx + wy * wy + wz * wz);
    }
    if (i == 0) *accum = 0.0f;
}

__global__ __launch_bounds__(NTHR) void chamfer_nn(const float4* __restrict__ cand,
                                                   float* __restrict__ res) {
    const int qb    = blockIdx.x % NQB;
    const int chunk = blockIdx.x / NQB;
    const int b     = blockIdx.y;
    const int dir   = blockIdx.z;   // 0: q=warped, db=pc2;  1: q=pc2, db=warped

    const float4* __restrict__ qarr =
        cand + ((size_t)(1 - dir) * BATCH + b) * N_PTS;
    const float4* __restrict__ db =
        cand + ((size_t)dir * BATCH + b) * N_PTS + (size_t)chunk * CHUNKC;

    const int q0 = qb * QPB + threadIdx.x;
    const int q1 = q0 + NTHR;

    float4 c0 = qarr[q0];
    float4 c1 = qarr[q1];
    const float qx0 = -0.5f * c0.x, qy0 = -0.5f * c0.y, qz0 = -0.5f * c0.z;
    const float qx1 = -0.5f * c1.x, qy1 = -0.5f * c1.y, qz1 = -0.5f * c1.z;
    const float q2_0 = c0.w, q2_1 = c1.w;

    float m0 = 3.402823466e38f, m1 = 3.402823466e38f;

    // Uniform address across the wave -> scalar (s_load) candidate fetches.
    #pragma unroll 8
    for (int j = 0; j < CHUNKC; ++j) {
        float4 c = db[j];
        float t0 = fmaf(qz0, c.z, c.w);
        t0 = fmaf(qy0, c.y, t0);
        t0 = fmaf(qx0, c.x, t0);
        m0 = fminf(m0, t0);
        float t1 = fmaf(qz1, c.z, c.w);
        t1 = fmaf(qy1, c.y, t1);
        t1 = fmaf(qx1, c.x, t1);
        m1 = fminf(m1, t1);
    }

    const size_t slot = ((size_t)dir * BATCH + b) * N_PTS;
    res[(size_t)chunk * TOTQ + slot + q0] = m0 + q2_0;   // full min d^2 for this chunk
    res[(size_t)chunk * TOTQ + slot + q1] = m1 + q2_1;
}

__global__ __launch_bounds__(256) void chamfer_reduce(const float* __restrict__ res,
                                                      float* __restrict__ accum) {
    const int i = blockIdx.x * 256 + threadIdx.x;   // query slot, < TOTQ
    float m = res[i];
    #pragma unroll
    for (int c = 1; c < NCHUNK; ++c)
        m = fminf(m, res[(size_t)c * TOTQ + i]);
    float v = sqrtf(fmaxf(m, 0.0f));

    for (int off = 32; off > 0; off >>= 1)
        v += __shfl_down(v, off, 64);

    __shared__ float wsum[4];
    const int wave = threadIdx.x >> 6;
    if ((threadIdx.x & 63) == 0) wsum[wave] = v;
    __syncthreads();
    if (threadIdx.x == 0)
        atomicAdd(accum, wsum[0] + wsum[1] + wsum[2] + wsum[3]);
}

__global__ void chamfer_finalize(const float* __restrict__ accum,
                                 float* __restrict__ out) {
    out[0] = accum[0] * (1.0f / (float)(BATCH * N_PTS));
}

extern "C" void kernel_launch(void* const* d_in, const int* in_sizes, int n_in,
                              void* d_out, int out_size, void* d_ws, size_t ws_size,
                              hipStream_t stream) {
    const float* pc1  = (const float*)d_in[0];
    const float* pc2  = (const float*)d_in[1];
    const float* flow = (const float*)d_in[2];
    float* out = (float*)d_out;

    float4* cand = (float4*)d_ws;
    float*  res  = (float*)(cand + 2 * BATCH * N_PTS);
    float*  accum = res + (size_t)NCHUNK * TOTQ;

    chamfer_prep<<<(BATCH * N_PTS + 255) / 256, 256, 0, stream>>>(pc1, pc2, flow, cand, accum);

    dim3 grid(NQB * NCHUNK, BATCH, 2);
    chamfer_nn<<<grid, NTHR, 0, stream>>>(cand, res);

    chamfer_reduce<<<TOTQ / 256, 256, 0, stream>>>(res, accum);
    chamfer_finalize<<<1, 1, 0, stream>>>(accum, out);
}

// Round 3
// 46.221 us; speedup vs baseline: 1.4466x; 1.1348x over previous
//
#include <hip/hip_runtime.h>
#include <math.h>

#define N_PTS   8192
#define BATCH   2
#define NTHR    256
#define QPT     4                       // queries per thread (registers)
#define QPB     (NTHR * QPT)            // 1024 queries per block
#define NQB     (N_PTS / QPB)           // 8 query-blocks per (b,dir)
#define NCHUNK  32
#define CHUNKC  (N_PTS / NCHUNK)        // 256 candidates per chunk (4 KB -> K$)
#define TOTQ    (BATCH * 2 * N_PTS)     // 32768 query slots
#define RBLK    (TOTQ / 256)            // 128 reduce blocks

// ws layout:
//   cand    : float4[2][BATCH][N_PTS]  set0 = pc2, set1 = pc1+flow   (512 KB)
//             cand[i] = (-2px, -2py, -2pz, |p|^2)
//   minbits : uint[TOTQ]               running min d^2 bits          (128 KB)
//   accum   : float
//   counter : uint

__global__ __launch_bounds__(256) void chamfer_prep(const float* __restrict__ pc1,
                                                    const float* __restrict__ pc2,
                                                    const float* __restrict__ flow,
                                                    float4* __restrict__ cand,
                                                    unsigned int* __restrict__ minbits,
                                                    float* __restrict__ accum,
                                                    unsigned int* __restrict__ counter) {
    int i = blockIdx.x * 256 + threadIdx.x;          // 0 .. TOTQ-1
    minbits[i] = 0x7F7FFFFFu;                        // FLT_MAX bits
    if (i < BATCH * N_PTS) {
        float px = pc2[i * 3 + 0], py = pc2[i * 3 + 1], pz = pc2[i * 3 + 2];
        cand[i] = make_float4(-2.f * px, -2.f * py, -2.f * pz,
                              px * px + py * py + pz * pz);
        float wx = pc1[i * 3 + 0] + flow[i * 3 + 0];
        float wy = pc1[i * 3 + 1] + flow[i * 3 + 1];
        float wz = pc1[i * 3 + 2] + flow[i * 3 + 2];
        cand[BATCH * N_PTS + i] = make_float4(-2.f * wx, -2.f * wy, -2.f * wz,
                                              wx * wx + wy * wy + wz * wz);
    }
    if (i == 0) { *accum = 0.0f; *counter = 0u; }
}

__global__ __launch_bounds__(NTHR) void chamfer_nn(const float4* __restrict__ cand,
                                                   unsigned int* __restrict__ minbits) {
    const int qb    = blockIdx.x % NQB;
    const int chunk = blockIdx.x / NQB;
    const int b     = blockIdx.y;
    const int dir   = blockIdx.z;   // 0: q=warped, db=pc2;  1: q=pc2, db=warped

    const float4* __restrict__ qarr =
        cand + ((size_t)(1 - dir) * BATCH + b) * N_PTS;
    const float4* __restrict__ db =
        cand + ((size_t)dir * BATCH + b) * N_PTS + (size_t)chunk * CHUNKC;

    const int q0 = qb * QPB + threadIdx.x;

    float qx[QPT], qy[QPT], qz[QPT], q2[QPT], m[QPT];
    #pragma unroll
    for (int k = 0; k < QPT; ++k) {
        float4 c = qarr[q0 + k * NTHR];
        qx[k] = -0.5f * c.x;
        qy[k] = -0.5f * c.y;
        qz[k] = -0.5f * c.z;
        q2[k] = c.w;
        m[k]  = 3.402823466e38f;
    }

    // Wave-uniform candidate stream -> scalar loads; 16 VALU ops per load.
    #pragma unroll 8
    for (int j = 0; j < CHUNKC; ++j) {
        float4 c = db[j];
        #pragma unroll
        for (int k = 0; k < QPT; ++k) {
            float t = fmaf(qz[k], c.z, c.w);
            t = fmaf(qy[k], c.y, t);
            t = fmaf(qx[k], c.x, t);
            m[k] = fminf(m[k], t);
        }
    }

    unsigned int* __restrict__ slot =
        minbits + ((size_t)dir * BATCH + b) * N_PTS;
    #pragma unroll
    for (int k = 0; k < QPT; ++k) {
        float d2 = fmaxf(m[k] + q2[k], 0.0f);   // clamp: uint ordering needs >= 0
        atomicMin(&slot[q0 + k * NTHR], __float_as_uint(d2));
    }
}

__global__ __launch_bounds__(256) void chamfer_reduce(const unsigned int* __restrict__ minbits,
                                                      float* __restrict__ accum,
                                                      unsigned int* __restrict__ counter,
                                                      float* __restrict__ out) {
    const int i = blockIdx.x * 256 + threadIdx.x;   // < TOTQ
    float v = sqrtf(__uint_as_float(minbits[i]));

    for (int off = 32; off > 0; off >>= 1)
        v += __shfl_down(v, off, 64);

    __shared__ float wsum[4];
    const int wave = threadIdx.x >> 6;
    if ((threadIdx.x & 63) == 0) wsum[wave] = v;
    __syncthreads();
    if (threadIdx.x == 0) {
        atomicAdd(accum, wsum[0] + wsum[1] + wsum[2] + wsum[3]);
        __threadfence();
        unsigned int old = atomicAdd(counter, 1u);
        if (old == RBLK - 1) {
            float total = atomicAdd(accum, 0.0f);   // coherent read-after-all-adds
            out[0] = total * (1.0f / (float)(BATCH * N_PTS));
        }
    }
}

extern "C" void kernel_launch(void* const* d_in, const int* in_sizes, int n_in,
                              void* d_out, int out_size, void* d_ws, size_t ws_size,
                              hipStream_t stream) {
    const float* pc1  = (const float*)d_in[0];
    const float* pc2  = (const float*)d_in[1];
    const float* flow = (const float*)d_in[2];
    float* out = (float*)d_out;

    float4* cand = (float4*)d_ws;
    unsigned int* minbits = (unsigned int*)(cand + 2 * BATCH * N_PTS);
    float* accum = (float*)(minbits + TOTQ);
    unsigned int* counter = (unsigned int*)(accum + 1);

    chamfer_prep<<<TOTQ / 256, 256, 0, stream>>>(pc1, pc2, flow, cand, minbits,
                                                 accum, counter);

    dim3 grid(NQB * NCHUNK, BATCH, 2);
    chamfer_nn<<<grid, NTHR, 0, stream>>>(cand, minbits);

    chamfer_reduce<<<RBLK, 256, 0, stream>>>(minbits, accum, counter, out);
}